// Round 12
// baseline (288.778 us; speedup 1.0000x reference)
//
#include <hip/hip_runtime.h>
#include <hip/hip_fp16.h>
#include <math.h>

#define N_NODES 50000
#define N_EDGES 800000
#define PAD_EDGES (N_EDGES + 8 * N_NODES)   // degree padded to >=8, multiple of 8
// dims: IN=128, HIDDEN=128, NUM_CLASSES=64 (hard-coded)
// Algebra: GraphConv chain is linear ->
//   logits = A^3 (h1 @ Wp) + t*c1 + d*c2 + bc
//   Wp = W1@W2@Wc, c1 = b1@W2@Wc, c2 = b2@Wc, d[v] = [deg_v>0] (=sum alpha), t = A d.

typedef _Float16 half8 __attribute__((ext_vector_type(8)));
typedef float floatx16 __attribute__((ext_vector_type(16)));

// ---------------- prep A: Wg -> hi/lo frags; W12 = W1@W2; c12 = b1@W2 ----------------
__global__ __launch_bounds__(256) void prep_a_k(const float* __restrict__ Wg,
                                                const float* __restrict__ W1,
                                                const float* __restrict__ W2,
                                                const float* __restrict__ b1,
                                                __half* __restrict__ Wg_hl,
                                                float* __restrict__ W12,
                                                float* __restrict__ c12) {
  int e = blockIdx.x * 256 + threadIdx.x;
  if (e < 16384) {
    _Float16* o = (_Float16*)Wg_hl;
    int k = e >> 7, n = e & 127;
    float w = Wg[k * 128 + n];
    _Float16 hi = (_Float16)w;
    float lo = w - (float)hi;
    int oi = (((k >> 3) * 128 + n) << 3) | (k & 7);
    o[oi] = hi;
    o[16384 + oi] = (_Float16)lo;
  } else if (e < 32768) {
    int local = e - 16384;
    int k = local >> 7, n = local & 127;
    float acc = 0.f;
    for (int j = 0; j < 128; ++j) acc = fmaf(W1[k * 128 + j], W2[j * 128 + n], acc);
    W12[k * 128 + n] = acc;
  } else if (e < 32896) {
    int n = e - 32768;
    float acc = 0.f;
    for (int j = 0; j < 128; ++j) acc = fmaf(b1[j], W2[j * 128 + n], acc);
    c12[n] = acc;
  }
}

// ---------------- prepP: Wp = W12@Wc -> hi/lo frags (NCOL=64); c1 = c12@Wc; c2 = b2@Wc ----------------
__global__ __launch_bounds__(256) void prepP_k(const float* __restrict__ W12,
                                               const float* __restrict__ c12,
                                               const float* __restrict__ Wc,
                                               const float* __restrict__ b2,
                                               __half* __restrict__ WPhl,
                                               float* __restrict__ c1,
                                               float* __restrict__ c2) {
  int e = blockIdx.x * 256 + threadIdx.x;
  _Float16* o = (_Float16*)WPhl;
  if (e < 8192) {
    int k = e >> 6, n = e & 63;
    float acc = 0.f;
    for (int j = 0; j < 128; ++j) acc = fmaf(W12[k * 128 + j], Wc[j * 64 + n], acc);
    _Float16 hi = (_Float16)acc;
    float lo = acc - (float)hi;
    int oi = (((k >> 3) * 64 + n) << 3) | (k & 7);
    o[oi] = hi;
    o[8192 + oi] = (_Float16)lo;
  } else if (e < 8256) {
    int n = e - 8192;
    float acc = 0.f;
    for (int j = 0; j < 128; ++j) acc = fmaf(c12[j], Wc[j * 64 + n], acc);
    c1[n] = acc;
  } else if (e < 8320) {
    int n = e - 8256;
    float acc = 0.f;
    for (int j = 0; j < 128; ++j) acc = fmaf(b2[j], Wc[j * 64 + n], acc);
    c2[n] = acc;
  }
}

// ---------------- MFMA GEMM: C16[M x NCOL] = fp16( A[M x 128] @ (Whi+Wlo) ) ----------------
template <int NCOL, bool A16, bool ELR>
__global__ __launch_bounds__(256) void mgemm_k(const void* __restrict__ Ap,
                                               const __half* __restrict__ Whl,
                                               __half* __restrict__ C16, int M,
                                               const float* __restrict__ al,
                                               const float* __restrict__ ar,
                                               float* __restrict__ el,
                                               float* __restrict__ er) {
  __shared__ __half Al[16][129][8];
  const int tid  = threadIdx.x;
  const int row0 = blockIdx.x * 128;
  const int lane = tid & 63;
  const int lane31 = lane & 31;
  const int q = lane >> 5;
  const int r = tid >> 6;

  if (A16) {
    const uint4* A8 = (const uint4*)Ap;
    #pragma unroll
    for (int i = 0; i < 8; ++i) {
      int idx = tid + i * 256;
      int row = idx >> 4, c = idx & 15;
      int grow = row0 + row;
      uint4 v = make_uint4(0u, 0u, 0u, 0u);
      if (grow < M) v = A8[grow * 16 + c];
      *reinterpret_cast<uint4*>(&Al[c][row][0]) = v;
    }
  } else {
    const float4* A4 = (const float4*)Ap;
    #pragma unroll
    for (int i = 0; i < 8; ++i) {
      int idx = tid + i * 256;
      int row = idx >> 4, c = idx & 15;
      int grow = row0 + row;
      half8 hv = {};
      if (grow < M) {
        float4 a0 = A4[grow * 32 + c * 2];
        float4 a1 = A4[grow * 32 + c * 2 + 1];
        hv[0] = (_Float16)a0.x; hv[1] = (_Float16)a0.y;
        hv[2] = (_Float16)a0.z; hv[3] = (_Float16)a0.w;
        hv[4] = (_Float16)a1.x; hv[5] = (_Float16)a1.y;
        hv[6] = (_Float16)a1.z; hv[7] = (_Float16)a1.w;
      }
      *reinterpret_cast<half8*>(&Al[c][row][0]) = hv;
    }
  }
  __syncthreads();

  half8 afr[8];
  #pragma unroll
  for (int s = 0; s < 8; ++s)
    afr[s] = *reinterpret_cast<const half8*>(&Al[2 * s + q][r * 32 + lane31][0]);

  const half8* B8 = reinterpret_cast<const half8*>(Whl);
  const int KN8 = 16 * NCOL;

  float elp[16], erp[16];
  if (ELR) {
    #pragma unroll
    for (int i = 0; i < 16; ++i) { elp[i] = 0.f; erp[i] = 0.f; }
  }

  #pragma unroll
  for (int tc = 0; tc < NCOL / 32; ++tc) {
    floatx16 acc = {};
    int nbase = tc * 32 + lane31;
    #pragma unroll
    for (int s = 0; s < 8; ++s) {
      int ci = (2 * s + q) * NCOL + nbase;
      half8 bl = B8[KN8 + ci];
      half8 bh = B8[ci];
      acc = __builtin_amdgcn_mfma_f32_32x32x16_f16(afr[s], bl, acc, 0, 0, 0);
      acc = __builtin_amdgcn_mfma_f32_32x32x16_f16(afr[s], bh, acc, 0, 0, 0);
    }
    if (ELR) {
      float alv = al[nbase], arv = ar[nbase];
      #pragma unroll
      for (int i = 0; i < 16; ++i) {
        elp[i] = fmaf(acc[i], alv, elp[i]);
        erp[i] = fmaf(acc[i], arv, erp[i]);
      }
    }
    #pragma unroll
    for (int i = 0; i < 16; ++i) {
      int rl = (i & 3) + 8 * (i >> 2) + 4 * q;
      int grow = row0 + r * 32 + rl;
      if (grow < M) C16[grow * NCOL + nbase] = __float2half(acc[i]);
    }
  }

  if (ELR) {
    #pragma unroll
    for (int off = 1; off <= 16; off <<= 1) {
      #pragma unroll
      for (int i = 0; i < 16; ++i) {
        elp[i] += __shfl_xor(elp[i], off);
        erp[i] += __shfl_xor(erp[i], off);
      }
    }
    if (lane31 == 0) {
      #pragma unroll
      for (int i = 0; i < 16; ++i) {
        int rl = (i & 3) + 8 * (i >> 2) + 4 * q;
        int grow = row0 + r * 32 + rl;
        if (grow < M) { el[grow] = elp[i]; er[grow] = erp[i]; }
      }
    }
  }
}

// ---------------- CSR build (padded slot count = max(8, round8(deg))) ----------------
__global__ __launch_bounds__(256) void hist_k(const int* __restrict__ dst,
                                              int* __restrict__ deg,
                                              int* __restrict__ rank, int E) {
  int e = blockIdx.x * 256 + threadIdx.x;
  if (e < E) rank[e] = atomicAdd(&deg[dst[e]], 1);
}

// merged scan1+scan2: per-block exclusive scan of padded degrees; the LAST block
// to finish also scans the block sums (no spin, no dispatch-order assumption).
__global__ __launch_bounds__(256) void scanA_k(const int* __restrict__ deg,
                                               int* __restrict__ offs,
                                               int* __restrict__ bsum,
                                               int* __restrict__ counter,
                                               int N, int nb) {
  __shared__ int s[256];
  __shared__ int lastdone;
  int t = threadIdx.x;
  int i = blockIdx.x * 256 + t;
  int v = 0;
  if (i < N) {
    int d = deg[i];
    v = (d + 7) & ~7;
    if (v < 8) v = 8;
  }
  s[t] = v;
  __syncthreads();
  for (int o = 1; o < 256; o <<= 1) {
    int add = (t >= o) ? s[t - o] : 0;
    __syncthreads();
    s[t] += add;
    __syncthreads();
  }
  if (i < N) offs[i] = s[t] - v;
  if (t == 255) {
    bsum[blockIdx.x] = s[255];
    __threadfence();
  }
  __syncthreads();
  if (t == 0) lastdone = (atomicAdd(counter, 1) == nb - 1) ? 1 : 0;
  __syncthreads();
  if (lastdone) {
    __threadfence();
    int v2 = (t < nb) ? bsum[t] : 0;
    s[t] = v2;
    __syncthreads();
    for (int o = 1; o < 256; o <<= 1) {
      int add = (t >= o) ? s[t - o] : 0;
      __syncthreads();
      s[t] += add;
      __syncthreads();
    }
    if (t < nb) bsum[t] = s[t] - v2;
  }
}

// scan3: finalize offs; pack el2[i] = {el[i], deg[i]>0}
__global__ __launch_bounds__(256) void scan3_k(int* __restrict__ offs,
                                               const int* __restrict__ deg,
                                               const int* __restrict__ bsum,
                                               const float* __restrict__ el,
                                               float2* __restrict__ el2, int N) {
  int i = blockIdx.x * 256 + threadIdx.x;
  if (i < N) {
    int o = offs[i] + bsum[blockIdx.x];
    offs[i] = o;
    int d = deg[i];
    el2[i] = make_float2(el[i], (d > 0) ? 1.f : 0.f);
    if (i == N - 1) {
      int pd = (d + 7) & ~7;
      if (pd < 8) pd = 8;
      offs[N] = o + pd;
    }
  }
}

// scatter writes meta directly: {src*16 | degflag(bit0), el[src] raw bits}.
// Later softmax rewrites it as {src*16, alpha}. csr_src array eliminated.
__global__ __launch_bounds__(256) void scatter_k(const int* __restrict__ src,
                                                 const int* __restrict__ dst,
                                                 const int* __restrict__ offs,
                                                 const int* __restrict__ rank,
                                                 const float2* __restrict__ el2,
                                                 int2* __restrict__ meta, int E) {
  int e = blockIdx.x * 256 + threadIdx.x;
  if (e < E) {
    int v = dst[e], s = src[e];
    float2 e2 = el2[s];
    int pos = offs[v] + rank[e];
    meta[pos] = make_int2((s * 16) | (e2.y != 0.f ? 1 : 0),
                          __float_as_int(e2.x));
  }
}

__device__ inline void fma8(float2 acc[4], uint4 u, float a) {
  __half2* h = reinterpret_cast<__half2*>(&u);
  #pragma unroll
  for (int j = 0; j < 4; ++j) {
    float2 f = __half22float2(h[j]);
    acc[j].x = fmaf(a, f.x, acc[j].x);
    acc[j].y = fmaf(a, f.y, acc[j].y);
  }
}

// ---------------- fused edge-softmax + t + agg 128 (GAT layer), LDS-staged meta ----------------
// Reads scatter-written meta {src*16|flag, el} sequentially (no random el gather here),
// computes alpha, rewrites meta {src*16, alpha} (pads {0,0}), stages per-wave LDS copy,
// aggregates mask-free. t[w] = sum alpha*flag.
__global__ __launch_bounds__(256) void aggsm_k(const int* __restrict__ offs,
                                               const int* __restrict__ deg,
                                               const float* __restrict__ er,
                                               int2* __restrict__ meta,
                                               float* __restrict__ t,
                                               const __half* __restrict__ hp,
                                               __half* __restrict__ out, int N) {
  __shared__ int2 lmeta[4][64];
  int wv   = threadIdx.x >> 6;
  int w    = (blockIdx.x * 256 + threadIdx.x) >> 6;
  int lane = threadIdx.x & 63;
  if (w >= N) return;
  int o0   = offs[w];
  int pcnt = offs[w + 1] - o0;
  int cnt  = deg[w];
  int q  = lane >> 4;
  int fl = lane & 15;
  const uint4* hpq = reinterpret_cast<const uint4*>(hp);

  if (cnt <= 64) {                       // wave-uniform fast path (covers cnt==0)
    bool valid = lane < cnt;
    float erv = er[w];
    int s16 = 0;
    float ev = -3.4e38f, flag = 0.f;
    if (valid) {
      int2 mr = meta[o0 + lane];
      s16 = mr.x & ~15;
      flag = (float)(mr.x & 1);
      float e0 = __int_as_float(mr.y) + erv;
      ev = (e0 >= 0.f) ? e0 : 0.2f * e0;
    }
    float m = ev;
    #pragma unroll
    for (int off = 32; off; off >>= 1) m = fmaxf(m, __shfl_xor(m, off));
    float ee = valid ? __expf(ev - m) : 0.f;
    float sum = ee, tp = ee * flag;
    #pragma unroll
    for (int off = 32; off; off >>= 1) {
      sum += __shfl_xor(sum, off);
      tp  += __shfl_xor(tp, off);
    }
    float inv = (cnt > 0) ? 1.f / sum : 0.f;
    int2 mm = make_int2(0, 0);
    if (valid) mm = make_int2(s16, __float_as_int(ee * inv));
    if (lane < pcnt) meta[o0 + lane] = mm;
    lmeta[wv][lane] = mm;
    if (lane == 0) t[w] = tp * inv;
  } else {                               // rare generic path (degree > 64)
    float erv = er[w];
    float m = -3.4e38f;
    for (int i = lane; i < cnt; i += 64) {
      int2 mr = meta[o0 + i];
      float ev = __int_as_float(mr.y) + erv;
      ev = (ev >= 0.f) ? ev : 0.2f * ev;
      m = fmaxf(m, ev);
    }
    #pragma unroll
    for (int off = 32; off; off >>= 1) m = fmaxf(m, __shfl_xor(m, off));
    float sum = 0.f, tacc = 0.f;
    int myS16 = 0; float myE = 0.f;
    for (int i = lane; i < cnt; i += 64) {
      int2 mr = meta[o0 + i];
      int s16 = mr.x & ~15;
      float flag = (float)(mr.x & 1);
      float ev = __int_as_float(mr.y) + erv;
      ev = (ev >= 0.f) ? ev : 0.2f * ev;
      float ee = __expf(ev - m);
      meta[o0 + i] = make_int2(s16, __float_as_int(ee));
      sum += ee;
      tacc += ee * flag;
      if (i == lane) { myS16 = s16; myE = ee; }
    }
    #pragma unroll
    for (int off = 32; off; off >>= 1) {
      sum  += __shfl_xor(sum, off);
      tacc += __shfl_xor(tacc, off);
    }
    float inv = 1.f / sum;
    if (lane == 0) t[w] = tacc * inv;
    for (int i = lane; i < cnt; i += 64) {
      int2 mm = meta[o0 + i];
      meta[o0 + i] = make_int2(mm.x, __float_as_int(__int_as_float(mm.y) * inv));
    }
    for (int i = cnt + lane; i < pcnt; i += 64) meta[o0 + i] = make_int2(0, 0);
    lmeta[wv][lane] = make_int2(myS16, __float_as_int(myE * inv));
  }

  // mask-free aggregation: LDS meta for first <=64 slots, global meta for rare tail.
  float2 acc0[4] = {}, acc1[4] = {};
  int pc = pcnt < 64 ? pcnt : 64;        // multiple of 8, >= 8
  int2 mA = lmeta[wv][q], mB = lmeta[wv][4 + q];
  for (int base = 8; base < pc; base += 8) {
    int2 nA = lmeta[wv][base + q], nB = lmeta[wv][base + 4 + q];
    uint4 vA = hpq[mA.x + fl], vB = hpq[mB.x + fl];
    fma8(acc0, vA, __int_as_float(mA.y));
    fma8(acc1, vB, __int_as_float(mB.y));
    mA = nA; mB = nB;
  }
  {
    uint4 vA = hpq[mA.x + fl], vB = hpq[mB.x + fl];
    fma8(acc0, vA, __int_as_float(mA.y));
    fma8(acc1, vB, __int_as_float(mB.y));
  }
  for (int p = o0 + 64 + q; p < o0 + pcnt; p += 4) {   // degree>64 tail (pads zeroed)
    int2 mm = meta[p];
    fma8(acc0, hpq[mm.x + fl], __int_as_float(mm.y));
  }
  #pragma unroll
  for (int j = 0; j < 4; ++j) { acc0[j].x += acc1[j].x; acc0[j].y += acc1[j].y; }
  #pragma unroll
  for (int off = 16; off <= 32; off <<= 1) {
    #pragma unroll
    for (int j = 0; j < 4; ++j) {
      acc0[j].x += __shfl_xor(acc0[j].x, off);
      acc0[j].y += __shfl_xor(acc0[j].y, off);
    }
  }
  if (q == 0) {
    float o8[8];
    #pragma unroll
    for (int j = 0; j < 4; ++j) { o8[2 * j] = acc0[j].x; o8[2 * j + 1] = acc0[j].y; }
    #pragma unroll
    for (int j = 0; j < 8; ++j) o8[j] = (o8[j] > 0.f) ? o8[j] : (__expf(o8[j]) - 1.f);
    __half2 p0 = __floats2half2_rn(o8[0], o8[1]);
    __half2 p1 = __floats2half2_rn(o8[2], o8[3]);
    __half2 p2 = __floats2half2_rn(o8[4], o8[5]);
    __half2 p3 = __floats2half2_rn(o8[6], o8[7]);
    uint4 pk;
    pk.x = *reinterpret_cast<unsigned*>(&p0);
    pk.y = *reinterpret_cast<unsigned*>(&p1);
    pk.z = *reinterpret_cast<unsigned*>(&p2);
    pk.w = *reinterpret_cast<unsigned*>(&p3);
    *reinterpret_cast<uint4*>(&out[w * 128 + fl * 8]) = pk;
  }
}

// ---------------- agg 64-feat via padded meta, mask-free, 2 slots in flight ----------------
template <bool FINAL>
__global__ __launch_bounds__(256) void agg64v_k(const int* __restrict__ offs,
                                                const int2* __restrict__ meta,
                                                const __half* __restrict__ zp,
                                                const float* __restrict__ t,
                                                const int* __restrict__ deg,
                                                const float* __restrict__ c1,
                                                const float* __restrict__ c2,
                                                const float* __restrict__ bc,
                                                void* __restrict__ outp, int N) {
  int w    = (blockIdx.x * 256 + threadIdx.x) >> 6;
  int lane = threadIdx.x & 63;
  if (w >= N) return;
  int o0 = offs[w], o1 = offs[w + 1];    // padded, multiple of 8
  int o   = lane >> 3;
  int fl  = lane & 7;
  const uint4* hpq = reinterpret_cast<const uint4*>(zp);

  float2 acc0[4] = {}, acc1[4] = {};
  int p = o0 + o;
  for (; p + 8 < o1; p += 16) {          // paired slots: 2 gathers in flight
    int2 mA = meta[p];
    int2 mB = meta[p + 8];
    uint4 vA = hpq[(mA.x >> 1) + fl];
    uint4 vB = hpq[(mB.x >> 1) + fl];
    fma8(acc0, vA, __int_as_float(mA.y));
    fma8(acc1, vB, __int_as_float(mB.y));
  }
  if (p < o1) {                           // odd remaining slot group
    int2 mA = meta[p];
    uint4 vA = hpq[(mA.x >> 1) + fl];
    fma8(acc0, vA, __int_as_float(mA.y));
  }
  #pragma unroll
  for (int j = 0; j < 4; ++j) { acc0[j].x += acc1[j].x; acc0[j].y += acc1[j].y; }
  #pragma unroll
  for (int off = 8; off <= 32; off <<= 1) {
    #pragma unroll
    for (int j = 0; j < 4; ++j) {
      acc0[j].x += __shfl_xor(acc0[j].x, off);
      acc0[j].y += __shfl_xor(acc0[j].y, off);
    }
  }
  if (o == 0) {
    float o8[8];
    #pragma unroll
    for (int j = 0; j < 4; ++j) { o8[2 * j] = acc0[j].x; o8[2 * j + 1] = acc0[j].y; }
    if (FINAL) {
      float tw = t[w];
      float dw = (deg[w] > 0) ? 1.f : 0.f;
      float4 a0 = reinterpret_cast<const float4*>(c1)[fl * 2];
      float4 a1 = reinterpret_cast<const float4*>(c1)[fl * 2 + 1];
      float4 d0 = reinterpret_cast<const float4*>(c2)[fl * 2];
      float4 d1 = reinterpret_cast<const float4*>(c2)[fl * 2 + 1];
      float4 b0 = reinterpret_cast<const float4*>(bc)[fl * 2];
      float4 b1v = reinterpret_cast<const float4*>(bc)[fl * 2 + 1];
      o8[0] += tw * a0.x + dw * d0.x + b0.x;
      o8[1] += tw * a0.y + dw * d0.y + b0.y;
      o8[2] += tw * a0.z + dw * d0.z + b0.z;
      o8[3] += tw * a0.w + dw * d0.w + b0.w;
      o8[4] += tw * a1.x + dw * d1.x + b1v.x;
      o8[5] += tw * a1.y + dw * d1.y + b1v.y;
      o8[6] += tw * a1.z + dw * d1.z + b1v.z;
      o8[7] += tw * a1.w + dw * d1.w + b1v.w;
      float4* of = reinterpret_cast<float4*>(outp);
      of[w * 16 + fl * 2]     = make_float4(o8[0], o8[1], o8[2], o8[3]);
      of[w * 16 + fl * 2 + 1] = make_float4(o8[4], o8[5], o8[6], o8[7]);
    } else {
      __half2 p0 = __floats2half2_rn(o8[0], o8[1]);
      __half2 p1 = __floats2half2_rn(o8[2], o8[3]);
      __half2 p2 = __floats2half2_rn(o8[4], o8[5]);
      __half2 p3 = __floats2half2_rn(o8[6], o8[7]);
      uint4 pk;
      pk.x = *reinterpret_cast<unsigned*>(&p0);
      pk.y = *reinterpret_cast<unsigned*>(&p1);
      pk.z = *reinterpret_cast<unsigned*>(&p2);
      pk.w = *reinterpret_cast<unsigned*>(&p3);
      reinterpret_cast<uint4*>(outp)[w * 8 + fl] = pk;
    }
  }
}

// ---------------- launch ----------------
extern "C" void kernel_launch(void* const* d_in, const int* in_sizes, int n_in,
                              void* d_out, int out_size, void* d_ws, size_t ws_size,
                              hipStream_t stream) {
  const float* x      = (const float*)d_in[0];
  const int*   src    = (const int*)d_in[1];
  const int*   dst    = (const int*)d_in[2];
  const float* W_gat  = (const float*)d_in[3];
  const float* attn_l = (const float*)d_in[4];
  const float* attn_r = (const float*)d_in[5];
  const float* W1     = (const float*)d_in[6];
  const float* b1     = (const float*)d_in[7];
  const float* W2     = (const float*)d_in[8];
  const float* b2     = (const float*)d_in[9];
  const float* Wc     = (const float*)d_in[10];
  const float* bc     = (const float*)d_in[11];
  float* out = (float*)d_out;

  char* ws = (char*)d_ws;
  size_t off = 0;
  auto walloc = [&](size_t bytes) -> void* {
    void* p = ws + off;
    off += (bytes + 255) & ~size_t(255);
    return p;
  };
  __half* P16     = (__half*)walloc((size_t)N_NODES * 128 * 2);  // h16 / z / z3
  __half* F16     = (__half*)walloc((size_t)N_NODES * 128 * 2);  // h1 / z2
  float*  el      = (float*)walloc((size_t)N_NODES * 4);
  float*  er      = (float*)walloc((size_t)N_NODES * 4);
  float2* el2     = (float2*)walloc((size_t)N_NODES * 8);
  float*  tbuf    = (float*)walloc((size_t)N_NODES * 4);
  int*    deg     = (int*)walloc((size_t)(N_NODES + 64) * 4);    // deg + scan counter
  int*    counter = deg + N_NODES;
  int*    offs    = (int*)walloc((size_t)(N_NODES + 1) * 4);
  int*    rank    = (int*)walloc((size_t)N_EDGES * 4);
  int2*   meta    = (int2*)walloc((size_t)PAD_EDGES * 8);
  int*    bsum    = (int*)walloc(1024);
  __half* Wg_hl   = (__half*)walloc((size_t)32768 * 2);
  __half* WP_hl   = (__half*)walloc((size_t)16384 * 2);
  float*  W12     = (float*)walloc((size_t)16384 * 4);
  float*  c12     = (float*)walloc((size_t)128 * 4);
  float*  c1      = (float*)walloc((size_t)64 * 4);
  float*  c2      = (float*)walloc((size_t)64 * 4);

  hipMemsetAsync(deg, 0, (size_t)(N_NODES + 64) * 4, stream);   // deg + counter

  const dim3 blk(256);
  const int nwave_blocks = (N_NODES + 3) / 4;
  const int nedge_blocks = (N_EDGES + 255) / 256;
  const int nscan_blocks = (N_NODES + 255) / 256;   // 196
  const int ngemm_blocks = (N_NODES + 127) / 128;   // 391

  prep_a_k<<<dim3(129), blk, 0, stream>>>(W_gat, W1, W2, b1, Wg_hl, W12, c12);
  prepP_k<<<dim3(33), blk, 0, stream>>>(W12, c12, Wc, b2, WP_hl, c1, c2);

  // h16 = fp16(x @ W_gat); el/er exact from f32 accs in epilogue
  mgemm_k<128, false, true><<<dim3(ngemm_blocks), blk, 0, stream>>>(
      x, Wg_hl, P16, N_NODES, attn_l, attn_r, el, er);

  hist_k<<<dim3(nedge_blocks), blk, 0, stream>>>(dst, deg, rank, N_EDGES);
  scanA_k<<<dim3(nscan_blocks), blk, 0, stream>>>(deg, offs, bsum, counter, N_NODES, nscan_blocks);
  scan3_k<<<dim3(nscan_blocks), blk, 0, stream>>>(offs, deg, bsum, el, el2, N_NODES);
  scatter_k<<<dim3(nedge_blocks), blk, 0, stream>>>(src, dst, offs, rank, el2, meta, N_EDGES);

  // fused: edge softmax (padded meta + t) + h1 = elu(A h16)  [F16]
  aggsm_k<<<dim3(nwave_blocks), blk, 0, stream>>>(offs, deg, er, meta, tbuf, P16, F16, N_NODES);
  // z = fp16(h1 @ Wp)  [P16, 64-dim]
  mgemm_k<64, true, false><<<dim3(ngemm_blocks), blk, 0, stream>>>(
      F16, WP_hl, P16, N_NODES, nullptr, nullptr, nullptr, nullptr);
  // z2 = A z  [F16], z3 = A z2  [P16], logits = A z3 + t*c1 + d*c2 + bc
  agg64v_k<false><<<dim3(nwave_blocks), blk, 0, stream>>>(offs, meta, P16, nullptr, nullptr, nullptr, nullptr, nullptr, F16, N_NODES);
  agg64v_k<false><<<dim3(nwave_blocks), blk, 0, stream>>>(offs, meta, F16, nullptr, nullptr, nullptr, nullptr, nullptr, P16, N_NODES);
  agg64v_k<true><<<dim3(nwave_blocks), blk, 0, stream>>>(offs, meta, P16, tbuf, deg, c1, c2, bc, out, N_NODES);
}